// Round 4
// baseline (524.828 us; speedup 1.0000x reference)
//
#include <hip/hip_runtime.h>
#include <hip/hip_bf16.h>
#include <cstddef>

#define NN 10000      // nodes
#define EE0 160000    // raw edges (self-loops added on top)
#define NF 14
#define DC 256        // per-head channels

static inline int ceildiv(int a, int b) { return (a + b - 1) / b; }

__device__ __forceinline__ float lrelu02(float x) { return fmaxf(x, 0.2f * x); }

// round-to-nearest-even fp32 -> bf16 (as raw short)
__device__ __forceinline__ short f2bf(float f) {
    unsigned u = __float_as_uint(f);
    unsigned r = (u + 0x7FFFu + ((u >> 16) & 1u)) >> 16;
    return (short)r;
}
__device__ __forceinline__ float bf2f(short s) {
    return __uint_as_float(((unsigned)(unsigned short)s) << 16);
}

typedef __attribute__((ext_vector_type(8))) short bf16x8;
typedef __attribute__((ext_vector_type(4))) float f32x4;

#define GLDS(gaddr, laddr)                                                         \
    __builtin_amdgcn_global_load_lds(                                              \
        (__attribute__((address_space(1))) void*)(gaddr),                          \
        (__attribute__((address_space(3))) void*)(laddr), 16, 0, 0)

// ---------------- CSR build ----------------
__global__ void count_edges_k(const int* __restrict__ ei, int* __restrict__ counts,
                              int E0, int N) {
    int e = blockIdx.x * 256 + threadIdx.x;
    int E = E0 + N;
    if (e >= E) return;
    int dst = (e < E0) ? ei[E0 + e] : (e - E0);
    atomicAdd(&counts[dst], 1);
}

// 1024 threads; each scans a contiguous chunk; one 1024-wide LDS scan (10 steps).
__global__ __launch_bounds__(1024) void scan_k(const int* __restrict__ counts,
                                               int* __restrict__ row_off, int n) {
    __shared__ int sums[1024];
    int t = threadIdx.x;
    int chunk = (n + 1023) >> 10;
    int base = t * chunk;
    int lim = base + chunk; if (lim > n) lim = n;
    int s = 0;
    for (int i = base; i < lim; ++i) s += counts[i];
    sums[t] = s;
    __syncthreads();
    for (int off = 1; off < 1024; off <<= 1) {
        int v = (t >= off) ? sums[t - off] : 0;
        __syncthreads();
        sums[t] += v;
        __syncthreads();
    }
    int run = (t == 0) ? 0 : sums[t - 1];   // exclusive prefix of this chunk
    for (int i = base; i < lim; ++i) { run += counts[i]; row_off[i + 1] = run; }
    if (t == 0) row_off[0] = 0;
}

__global__ void scatter_k(const int* __restrict__ ei, const int* __restrict__ row_off,
                          int* __restrict__ cursor, int* __restrict__ csr_src,
                          int E0, int N) {
    int e = blockIdx.x * 256 + threadIdx.x;
    int E = E0 + N;
    if (e >= E) return;
    int src, dst;
    if (e < E0) { src = ei[e]; dst = ei[E0 + e]; }
    else        { src = dst = e - E0; }
    int pos = row_off[dst] + atomicAdd(&cursor[dst], 1);
    csr_src[pos] = src;
}

// ---------------- fused fp32 -> bf16 weight conversion (4 segments) ----------------
__global__ __launch_bounds__(256) void cvt_bf16_fused_k(
    const float* __restrict__ p0, short* __restrict__ q0, int n0,
    const float* __restrict__ p1, short* __restrict__ q1, int n1,
    const float* __restrict__ p2, short* __restrict__ q2, int n2,
    const float* __restrict__ p3, short* __restrict__ q3, int n3) {
    int i = blockIdx.x * 256 + threadIdx.x;
    const float* in; short* out; int idx;
    if (i < n0) { in = p0; out = q0; idx = i; }
    else if (i < n0 + n1) { in = p1; out = q1; idx = i - n0; }
    else if (i < n0 + n1 + n2) { in = p2; out = q2; idx = i - n0 - n1; }
    else if (i < n0 + n1 + n2 + n3) { in = p3; out = q3; idx = i - n0 - n1 - n2; }
    else return;
    float4 v = ((const float4*)in)[idx];
    short4 o;
    o.x = f2bf(v.x); o.y = f2bf(v.y); o.z = f2bf(v.z); o.w = f2bf(v.w);
    ((short4*)out)[idx] = o;
}

// ---------------- K-pad fp32 [rows,K] -> bf16 [rows,Kp] (zero tail), 3 segments ----
__global__ __launch_bounds__(256) void pad_bf16_k(
    const float* __restrict__ p0, short* __restrict__ q0, int r0,
    const float* __restrict__ p1, short* __restrict__ q1, int r1,
    const float* __restrict__ p2, short* __restrict__ q2, int r2,
    int K, int Kp) {
    int i = blockIdx.x * 256 + threadIdx.x;
    int rows = r0 + r1 + r2;
    int total = rows * Kp;
    if (i >= total) return;
    int row = i / Kp, col = i - row * Kp;
    const float* in; short* out; int r;
    if (row < r0) { in = p0; out = q0; r = row; }
    else if (row < r0 + r1) { in = p1; out = q1; r = row - r0; }
    else { in = p2; out = q2; r = row - r0 - r1; }
    out[(size_t)r * Kp + col] = (col < K) ? f2bf(in[(size_t)r * K + col]) : (short)0;
}

// ---------------- dual-output bf16 MFMA GEMM (round-2 config: BK=32, 16KB LDS) ----
// Fused alpha writes non-atomic per-64-col-chunk partials ps/pd[chunk][m];
// alpha_reduce_k folds them into asrc/adst.
__global__ __launch_bounds__(256) void gemm_bf16_dual(
    const short* __restrict__ A, const short* __restrict__ B,
    const float* __restrict__ b1, const float* __restrict__ b2,
    const float* __restrict__ a_s, const float* __restrict__ a_d,
    float* __restrict__ ps, float* __restrict__ pd,
    short* __restrict__ Cb, void* __restrict__ Cf, int lin_bf16,
    int M, int Nh, int Nf, int K, int H) {
    __shared__ short As[128 * 32];
    __shared__ short Bs[128 * 32];
    const int t = threadIdx.x;
    const int wave = t >> 6, lane = t & 63;
    const int m0 = blockIdx.y * 128, n0 = blockIdx.x * 128;
    const int wm = (wave >> 1) * 64, wn = (wave & 1) * 64;
    const int lane15 = lane & 15, quad = lane >> 4;

    const int lrow = lane >> 2;                        // row within 16-row wave region
    const int lk = ((lane & 3) ^ ((lrow >> 1) & 3)) * 8;  // swizzled global k chunk
    int arow0 = m0 + wave * 16 + lrow;
    int arow1 = arow0 + 64;
    if (arow0 > M - 1) arow0 = M - 1;
    if (arow1 > M - 1) arow1 = M - 1;
    const short* ag0 = A + (size_t)arow0 * K + lk;
    const short* ag1 = A + (size_t)arow1 * K + lk;
    const short* bg0 = B + (size_t)(n0 + wave * 16 + lrow) * K + lk;
    const short* bg1 = B + (size_t)(n0 + 64 + wave * 16 + lrow) * K + lk;
    short* al0 = &As[(wave * 16) * 32];
    short* al1 = &As[(64 + wave * 16) * 32];
    short* bl0 = &Bs[(wave * 16) * 32];
    short* bl1 = &Bs[(64 + wave * 16) * 32];

    const int rql = (quad ^ ((lane15 >> 1) & 3)) * 8;  // swizzled read position

    f32x4 acc[4][4];
#pragma unroll
    for (int i = 0; i < 4; ++i)
#pragma unroll
        for (int j = 0; j < 4; ++j) acc[i][j] = (f32x4){0.f, 0.f, 0.f, 0.f};

    for (int k0 = 0; k0 < K; k0 += 32) {
        GLDS(ag0 + k0, al0);
        GLDS(ag1 + k0, al1);
        GLDS(bg0 + k0, bl0);
        GLDS(bg1 + k0, bl1);
        __syncthreads();
        bf16x8 af[4], bfr[4];
#pragma unroll
        for (int i = 0; i < 4; ++i)
            af[i] = *(const bf16x8*)&As[(wm + 16 * i + lane15) * 32 + rql];
#pragma unroll
        for (int j = 0; j < 4; ++j)
            bfr[j] = *(const bf16x8*)&Bs[(wn + 16 * j + lane15) * 32 + rql];
#pragma unroll
        for (int i = 0; i < 4; ++i)
#pragma unroll
            for (int j = 0; j < 4; ++j)
                acc[i][j] = __builtin_amdgcn_mfma_f32_16x16x32_bf16(
                    af[i], bfr[j], acc[i][j], 0, 0, 0);
        __syncthreads();
    }

    if (n0 >= Nh) {
        // linear-skip part: bias folded in; fp32 (layer 3 -> out) or bf16 (1-2)
#pragma unroll
        for (int j = 0; j < 4; ++j) {
            int nc = n0 - Nh + wn + 16 * j + lane15;
            float bias = b1[nc] + b2[nc];
#pragma unroll
            for (int i = 0; i < 4; ++i) {
                int mb = m0 + wm + 16 * i + quad * 4;
#pragma unroll
                for (int r = 0; r < 4; ++r) {
                    int m = mb + r;
                    if (m < M) {
                        float v = acc[i][j][r] + bias;
                        if (lin_bf16) ((short*)Cf)[(size_t)m * Nf + nc] = f2bf(v);
                        else          ((float*)Cf)[(size_t)m * Nf + nc] = v;
                    }
                }
            }
        }
    } else {
        // h part: store bf16 h + fused alpha chunk-partials (non-atomic).
        const int chunk = (n0 + wn) >> 6;
        const int head = chunk >> 2;               // DC=256 -> 4 chunks/head
        const int cb = (n0 + wn) & 255;
        float asv[4], adv[4];
#pragma unroll
        for (int j = 0; j < 4; ++j) {
            asv[j] = a_s[head * DC + cb + 16 * j + lane15];
            adv[j] = a_d[head * DC + cb + 16 * j + lane15];
        }
#pragma unroll
        for (int j = 0; j < 4; ++j) {
            int n = n0 + wn + 16 * j + lane15;
#pragma unroll
            for (int i = 0; i < 4; ++i) {
                int mb = m0 + wm + 16 * i + quad * 4;
#pragma unroll
                for (int r = 0; r < 4; ++r) {
                    int m = mb + r;
                    if (m < M) Cb[(size_t)m * Nh + n] = f2bf(acc[i][j][r]);
                }
            }
        }
        float* psc = ps + (size_t)chunk * M;
        float* pdc = pd + (size_t)chunk * M;
#pragma unroll
        for (int i = 0; i < 4; ++i) {
#pragma unroll
            for (int r = 0; r < 4; ++r) {
                float s = acc[i][0][r] * asv[0] + acc[i][1][r] * asv[1] +
                          acc[i][2][r] * asv[2] + acc[i][3][r] * asv[3];
                float d = acc[i][0][r] * adv[0] + acc[i][1][r] * adv[1] +
                          acc[i][2][r] * adv[2] + acc[i][3][r] * adv[3];
#pragma unroll
                for (int off = 8; off > 0; off >>= 1) {   // reduce 16 lanes (same quad)
                    s += __shfl_xor(s, off);
                    d += __shfl_xor(d, off);
                }
                int m = m0 + wm + 16 * i + quad * 4 + r;
                if (lane15 == 0 && m < M) { psc[m] = s; pdc[m] = d; }
            }
        }
    }
}

// ---------------- fold per-chunk alpha partials -> asrc/adst [M,H] ----------------
__global__ __launch_bounds__(256) void alpha_reduce_k(
    const float* __restrict__ ps, const float* __restrict__ pd,
    float* __restrict__ asrc, float* __restrict__ adst, int M, int H) {
    int m = blockIdx.x * 256 + threadIdx.x;
    int h = blockIdx.y;
    if (m >= M) return;
    float s = 0.f, d = 0.f;
#pragma unroll
    for (int c = 0; c < 4; ++c) {                  // 4 chunks per 256-wide head
        s += ps[(size_t)(h * 4 + c) * M + m];
        d += pd[(size_t)(h * 4 + c) * M + m];
    }
    asrc[m * H + h] = s;
    adst[m * H + h] = d;
}

// ---------------- edge softmax coefficients, one wave per (node, head-pair) -------
// Writes cp[hp*E + e] = (coef_headA, coef_headB). Removes all cross-lane work
// from the payload aggregation kernels.
__global__ __launch_bounds__(256) void coef_k(
    const float* __restrict__ asrc, const float* __restrict__ adst_a,
    const int* __restrict__ row_off, const int* __restrict__ csr_src,
    float2* __restrict__ cp, int N, int H, int E) {
    int wid = (int)((blockIdx.x * (size_t)blockDim.x + threadIdx.x) >> 6);
    int lane = threadIdx.x & 63;
    int HP = H >> 1;
    if (wid >= N * HP) return;
    int n = wid / HP, hp = wid - n * HP;
    int hA = hp * 2;
    int beg = row_off[n], end = row_off[n + 1];
    int deg = end - beg;
    const float2 adp = *(const float2*)(adst_a + (size_t)n * H + hA);
    float2* cpp = cp + (size_t)hp * E;

    if (deg <= 64) {
        int s = 0; float eA = -1e38f, eB = -1e38f;
        if (lane < deg) {
            s = csr_src[beg + lane];
            float2 av = *(const float2*)(asrc + (size_t)s * H + hA);
            eA = lrelu02(av.x + adp.x);
            eB = lrelu02(av.y + adp.y);
        }
        float mA = eA, mB = eB;
#pragma unroll
        for (int off = 32; off > 0; off >>= 1) {
            mA = fmaxf(mA, __shfl_xor(mA, off));
            mB = fmaxf(mB, __shfl_xor(mB, off));
        }
        float pA = (lane < deg) ? __expf(eA - mA) : 0.f;
        float pB = (lane < deg) ? __expf(eB - mB) : 0.f;
        float sA = pA, sB = pB;
#pragma unroll
        for (int off = 32; off > 0; off >>= 1) {
            sA += __shfl_xor(sA, off);
            sB += __shfl_xor(sB, off);
        }
        if (lane < deg)
            cpp[beg + lane] = make_float2(pA / (sA + 1e-16f), pB / (sB + 1e-16f));
    } else {
        float mA = -1e38f, mB = -1e38f;
        for (int i = beg + lane; i < end; i += 64) {
            int s = csr_src[i];
            float2 av = *(const float2*)(asrc + (size_t)s * H + hA);
            mA = fmaxf(mA, lrelu02(av.x + adp.x));
            mB = fmaxf(mB, lrelu02(av.y + adp.y));
        }
#pragma unroll
        for (int off = 32; off > 0; off >>= 1) {
            mA = fmaxf(mA, __shfl_xor(mA, off));
            mB = fmaxf(mB, __shfl_xor(mB, off));
        }
        float sA = 0.f, sB = 0.f;
        for (int i = beg + lane; i < end; i += 64) {
            int s = csr_src[i];
            float2 av = *(const float2*)(asrc + (size_t)s * H + hA);
            sA += __expf(lrelu02(av.x + adp.x) - mA);
            sB += __expf(lrelu02(av.y + adp.y) - mB);
        }
#pragma unroll
        for (int off = 32; off > 0; off >>= 1) {
            sA += __shfl_xor(sA, off);
            sB += __shfl_xor(sB, off);
        }
        float invA = 1.f / (sA + 1e-16f);
        float invB = 1.f / (sB + 1e-16f);
        for (int i = beg + lane; i < end; i += 64) {
            int s = csr_src[i];
            float2 av = *(const float2*)(asrc + (size_t)s * H + hA);
            cpp[i] = make_float2(__expf(lrelu02(av.x + adp.x) - mA) * invA,
                                 __expf(lrelu02(av.y + adp.y) - mB) * invB);
        }
    }
}

// ---------------- GAT aggregation: pure payload, one wave per (node, head-pair) ---
// beg/end hoisted to SGPR via readfirstlane; per-edge src + coef read as
// wave-uniform scalar loads; 16B/lane coalesced payload, 8-deep; no cross-lane.
__global__ __launch_bounds__(256) void gat_agg(
    const short* __restrict__ hbuf, const short* __restrict__ lin,
    const float2* __restrict__ cp, const int* __restrict__ row_off,
    const int* __restrict__ csr_src, short* __restrict__ outx,
    int N, int H, int E) {
    int wid = (int)((blockIdx.x * (size_t)blockDim.x + threadIdx.x) >> 6);
    int lane = threadIdx.x & 63;
    int HP = H >> 1;
    if (wid >= N * HP) return;
    int n = wid / HP, hp = wid - n * HP;
    int hA = hp * 2;
    const int beg = __builtin_amdgcn_readfirstlane(row_off[n]);
    const int end = __builtin_amdgcn_readfirstlane(row_off[n + 1]);
    const bool loH = (lane < 32);

    size_t cbase = (size_t)n * (H * DC) + (size_t)hA * DC + lane * 8;  // 8 ch/lane
    float acc[8];
    {
        bf16x8 lv = *(const bf16x8*)(lin + cbase);
#pragma unroll
        for (int j = 0; j < 8; ++j) acc[j] = bf2f(lv[j]);
    }
    const size_t hoff = (size_t)hA * DC + lane * 8;
    const float2* cpp = cp + (size_t)hp * E;

    int i = beg;
    for (; i + 8 <= end; i += 8) {
        int su[8]; float2 w[8];
#pragma unroll
        for (int u = 0; u < 8; ++u) { su[u] = csr_src[i + u]; w[u] = cpp[i + u]; }
        bf16x8 v[8];
#pragma unroll
        for (int u = 0; u < 8; ++u)
            v[u] = *(const bf16x8*)(hbuf + (size_t)su[u] * (H * DC) + hoff);
#pragma unroll
        for (int u = 0; u < 8; ++u) {
            float wv = loH ? w[u].x : w[u].y;
#pragma unroll
            for (int j = 0; j < 8; ++j) acc[j] += wv * bf2f(v[u][j]);
        }
    }
    for (; i < end; ++i) {
        int su = csr_src[i];
        float2 wp = cpp[i];
        float wv = loH ? wp.x : wp.y;
        const bf16x8 hv = *(const bf16x8*)(hbuf + (size_t)su * (H * DC) + hoff);
#pragma unroll
        for (int j = 0; j < 8; ++j) acc[j] += wv * bf2f(hv[j]);
    }
    // ELU + bf16
    bf16x8 o;
#pragma unroll
    for (int j = 0; j < 8; ++j) {
        float a = acc[j];
        a = a > 0.f ? a : __expf(a) - 1.f;
        o[j] = f2bf(a);
    }
    *(bf16x8*)(outx + cbase) = o;
}

// ---------------- Layer-3 aggregation: one block (3 waves = 3 head-pairs)/node ----
__global__ __launch_bounds__(192) void gat_agg_mean(
    const short* __restrict__ hbuf, const float2* __restrict__ cp,
    const int* __restrict__ row_off, const int* __restrict__ csr_src,
    float* __restrict__ out, int N, int E) {
    const int H = 6;
    __shared__ float red[6][DC];
    int n = blockIdx.x;
    int wave = threadIdx.x >> 6, lane = threadIdx.x & 63;
    int hp = wave, hA = hp * 2;
    const int beg = __builtin_amdgcn_readfirstlane(row_off[n]);
    const int end = __builtin_amdgcn_readfirstlane(row_off[n + 1]);
    const float invH = 1.f / 6.f;
    const bool loH = (lane < 32);

    float acc[8];
#pragma unroll
    for (int j = 0; j < 8; ++j) acc[j] = 0.f;
    const size_t hoff = (size_t)hA * DC + lane * 8;
    const float2* cpp = cp + (size_t)hp * E;

    int i = beg;
    for (; i + 8 <= end; i += 8) {
        int su[8]; float2 w[8];
#pragma unroll
        for (int u = 0; u < 8; ++u) { su[u] = csr_src[i + u]; w[u] = cpp[i + u]; }
        bf16x8 v[8];
#pragma unroll
        for (int u = 0; u < 8; ++u)
            v[u] = *(const bf16x8*)(hbuf + (size_t)su[u] * (H * DC) + hoff);
#pragma unroll
        for (int u = 0; u < 8; ++u) {
            float wv = loH ? w[u].x : w[u].y;
#pragma unroll
            for (int j = 0; j < 8; ++j) acc[j] += wv * bf2f(v[u][j]);
        }
    }
    for (; i < end; ++i) {
        int su = csr_src[i];
        float2 wp = cpp[i];
        float wv = loH ? wp.x : wp.y;
        const bf16x8 hv = *(const bf16x8*)(hbuf + (size_t)su * (H * DC) + hoff);
#pragma unroll
        for (int j = 0; j < 8; ++j) acc[j] += wv * bf2f(hv[j]);
    }
#pragma unroll
    for (int j = 0; j < 8; ++j) acc[j] *= invH;   // mean over 6 heads
    {
        int head = hA + (loH ? 0 : 1);
        int ch0 = (lane & 31) * 8;
        *(float4*)&red[head][ch0]     = make_float4(acc[0], acc[1], acc[2], acc[3]);
        *(float4*)&red[head][ch0 + 4] = make_float4(acc[4], acc[5], acc[6], acc[7]);
    }
    __syncthreads();
    if (wave == 0) {
        float* op = out + (size_t)n * DC + lane * 4;
        float4 o = *(float4*)op;   // lin3 + b3 + lb3 preloaded by GEMM
#pragma unroll
        for (int j = 0; j < 6; ++j) {
            float4 r = *(float4*)&red[j][lane * 4];
            o.x += r.x; o.y += r.y; o.z += r.z; o.w += r.w;
        }
        *(float4*)op = o;
    }
}

// ---------------- launch ----------------
extern "C" void kernel_launch(void* const* d_in, const int* in_sizes, int n_in,
                              void* d_out, int out_size, void* d_ws, size_t ws_size,
                              hipStream_t stream) {
    const float* x   = (const float*)d_in[0];
    const int*   ei  = (const int*)d_in[1];
    const float* W1  = (const float*)d_in[2];
    const float* a1s = (const float*)d_in[3];
    const float* a1d = (const float*)d_in[4];
    const float* b1  = (const float*)d_in[5];
    const float* lw1 = (const float*)d_in[6];
    const float* lb1 = (const float*)d_in[7];
    const float* W2  = (const float*)d_in[8];
    const float* a2s = (const float*)d_in[9];
    const float* a2d = (const float*)d_in[10];
    const float* b2  = (const float*)d_in[11];
    const float* lb2_w = (const float*)d_in[12];
    const float* lb2 = (const float*)d_in[13];
    const float* W3  = (const float*)d_in[14];
    const float* a3s = (const float*)d_in[15];
    const float* a3d = (const float*)d_in[16];
    const float* b3  = (const float*)d_in[17];
    const float* lw3 = (const float*)d_in[18];
    const float* lb3 = (const float*)d_in[19];
    const float* lw2 = lb2_w;
    float* out = (float*)d_out;

    const int N = NN, E0 = EE0, E = EE0 + NN;

    unsigned char* w = (unsigned char*)d_ws;
    size_t off = 0;
    auto alloc = [&](size_t bytes) {
        void* p = w + off;
        off += (bytes + 255) & ~(size_t)255;
        return p;
    };
    short* hbuf   = (short*)alloc((size_t)N * 1536 * 2);  // h bf16 (max: layer 3)
    short* buf    = (short*)alloc((size_t)N * 1024 * 2);  // lin1/lin2 skip, bf16
    short* xb     = (short*)alloc((size_t)N * 1024 * 2);  // x1 bf16, then x2 bf16
    short* xpad   = (short*)alloc((size_t)N * 32 * 2);    // x zero-padded K=32 bf16
    short* W1p    = (short*)alloc((size_t)1024 * 32 * 2);       // + lw1p right after
    short* lw1p   = (short*)alloc((size_t)1024 * 32 * 2);
    short* W2b    = (short*)alloc((size_t)1024 * 1024 * 2);     // + lw2b right after
    short* lw2b   = (short*)alloc((size_t)1024 * 1024 * 2);
    short* W3b    = (short*)alloc((size_t)1536 * 1024 * 2);     // + lw3b right after
    short* lw3b   = (short*)alloc((size_t)256 * 1024 * 2);
    float* psrc   = (float*)alloc((size_t)24 * N * 4);   // alpha chunk-partials (src)
    float* pdst   = (float*)alloc((size_t)24 * N * 4);   // alpha chunk-partials (dst)
    float* asrc   = (float*)alloc((size_t)N * 6 * 4);
    float* adst   = (float*)alloc((size_t)N * 6 * 4);
    float2* cp    = (float2*)alloc((size_t)3 * E * 8);   // edge coef pairs (max HP=3)
    int* row_off  = (int*)alloc((size_t)(N + 1) * 4);
    int* counts2  = (int*)alloc((size_t)2 * N * 4);  // counts | cursor
    int* counts   = counts2;
    int* cursor   = counts2 + N;
    int* csr_src  = (int*)alloc((size_t)E * 4);
    (void)ws_size; (void)n_in; (void)in_sizes; (void)out_size;

    // ---- CSR build ----
    hipMemsetAsync(counts2, 0, (size_t)2 * N * 4, stream);
    count_edges_k<<<ceildiv(E, 256), 256, 0, stream>>>(ei, counts, E0, N);
    scan_k<<<1, 1024, 0, stream>>>(counts, row_off, N);
    scatter_k<<<ceildiv(E, 256), 256, 0, stream>>>(ei, row_off, cursor, csr_src, E0, N);

    // ---- weight bf16 conversion (fused) + K-pad for layer 1 ----
    {
        int q0 = 1024 * 1024 / 4, q1 = 1024 * 1024 / 4, q2 = 1536 * 1024 / 4,
            q3 = 256 * 1024 / 4;
        cvt_bf16_fused_k<<<ceildiv(q0 + q1 + q2 + q3, 256), 256, 0, stream>>>(
            W2, W2b, q0, lw2, lw2b, q1, W3, W3b, q2, lw3, lw3b, q3);
        int rows = N + 1024 + 1024;
        pad_bf16_k<<<ceildiv(rows * 32, 256), 256, 0, stream>>>(
            x, xpad, N, W1, W1p, 1024, lw1, lw1p, 1024, NF, 32);
    }

    // ---- Layer 1 (H=4, K=14 padded to 32): h->hbuf bf16, lin->buf bf16 ----
    gemm_bf16_dual<<<dim3(16, ceildiv(N, 128)), 256, 0, stream>>>(
        xpad, W1p, b1, lb1, a1s, a1d, psrc, pdst, hbuf, (void*)buf, 1,
        N, 1024, 1024, 32, 4);
    alpha_reduce_k<<<dim3(ceildiv(N, 256), 4), 256, 0, stream>>>(
        psrc, pdst, asrc, adst, N, 4);
    coef_k<<<ceildiv(N * 2, 4), 256, 0, stream>>>(asrc, adst, row_off, csr_src,
                                                  cp, N, 4, E);
    gat_agg<<<ceildiv(N * 2, 4), 256, 0, stream>>>(hbuf, buf, cp, row_off,
                                                   csr_src, xb, N, 4, E);

    // ---- Layer 2 (H=4, K=1024) ----
    gemm_bf16_dual<<<dim3(16, ceildiv(N, 128)), 256, 0, stream>>>(
        xb, W2b, b2, lb2, a2s, a2d, psrc, pdst, hbuf, (void*)buf, 1,
        N, 1024, 1024, 1024, 4);
    alpha_reduce_k<<<dim3(ceildiv(N, 256), 4), 256, 0, stream>>>(
        psrc, pdst, asrc, adst, N, 4);
    coef_k<<<ceildiv(N * 2, 4), 256, 0, stream>>>(asrc, adst, row_off, csr_src,
                                                  cp, N, 4, E);
    gat_agg<<<ceildiv(N * 2, 4), 256, 0, stream>>>(hbuf, buf, cp, row_off,
                                                   csr_src, xb, N, 4, E);

    // ---- Layer 3 (H=6, K=1024, mean heads): h->hbuf, lin->out fp32 ----
    gemm_bf16_dual<<<dim3(14, ceildiv(N, 128)), 256, 0, stream>>>(
        xb, W3b, b3, lb3, a3s, a3d, psrc, pdst, hbuf, (void*)out, 0,
        N, 1536, 256, 1024, 6);
    alpha_reduce_k<<<dim3(ceildiv(N, 256), 6), 256, 0, stream>>>(
        psrc, pdst, asrc, adst, N, 6);
    coef_k<<<ceildiv(N * 3, 4), 256, 0, stream>>>(asrc, adst, row_off, csr_src,
                                                  cp, N, 6, E);
    gat_agg_mean<<<N, 192, 0, stream>>>(hbuf, cp, row_off, csr_src, out, N, E);
}

// Round 5
// 442.462 us; speedup vs baseline: 1.1862x; 1.1862x over previous
//
#include <hip/hip_runtime.h>
#include <hip/hip_bf16.h>
#include <cstddef>

#define NN 10000      // nodes
#define EE0 160000    // raw edges (self-loops added on top)
#define NF 14
#define DC 256        // per-head channels

static inline int ceildiv(int a, int b) { return (a + b - 1) / b; }

__device__ __forceinline__ float lrelu02(float x) { return fmaxf(x, 0.2f * x); }

// round-to-nearest-even fp32 -> bf16 (as raw short)
__device__ __forceinline__ short f2bf(float f) {
    unsigned u = __float_as_uint(f);
    unsigned r = (u + 0x7FFFu + ((u >> 16) & 1u)) >> 16;
    return (short)r;
}
__device__ __forceinline__ float bf2f(short s) {
    return __uint_as_float(((unsigned)(unsigned short)s) << 16);
}

typedef __attribute__((ext_vector_type(8))) short bf16x8;
typedef __attribute__((ext_vector_type(4))) float f32x4;

#define GLDS(gaddr, laddr)                                                         \
    __builtin_amdgcn_global_load_lds(                                              \
        (__attribute__((address_space(1))) void*)(gaddr),                          \
        (__attribute__((address_space(3))) void*)(laddr), 16, 0, 0)

// ---------------- CSR build ----------------
__global__ void count_edges_k(const int* __restrict__ ei, int* __restrict__ counts,
                              int E0, int N) {
    int e = blockIdx.x * 256 + threadIdx.x;
    int E = E0 + N;
    if (e >= E) return;
    int dst = (e < E0) ? ei[E0 + e] : (e - E0);
    atomicAdd(&counts[dst], 1);
}

// 1024 threads; each scans a contiguous chunk; one 1024-wide LDS scan (10 steps).
__global__ __launch_bounds__(1024) void scan_k(const int* __restrict__ counts,
                                               int* __restrict__ row_off, int n) {
    __shared__ int sums[1024];
    int t = threadIdx.x;
    int chunk = (n + 1023) >> 10;
    int base = t * chunk;
    int lim = base + chunk; if (lim > n) lim = n;
    int s = 0;
    for (int i = base; i < lim; ++i) s += counts[i];
    sums[t] = s;
    __syncthreads();
    for (int off = 1; off < 1024; off <<= 1) {
        int v = (t >= off) ? sums[t - off] : 0;
        __syncthreads();
        sums[t] += v;
        __syncthreads();
    }
    int run = (t == 0) ? 0 : sums[t - 1];   // exclusive prefix of this chunk
    for (int i = base; i < lim; ++i) { run += counts[i]; row_off[i + 1] = run; }
    if (t == 0) row_off[0] = 0;
}

__global__ void scatter_k(const int* __restrict__ ei, const int* __restrict__ row_off,
                          int* __restrict__ cursor, int* __restrict__ csr_src,
                          int E0, int N) {
    int e = blockIdx.x * 256 + threadIdx.x;
    int E = E0 + N;
    if (e >= E) return;
    int src, dst;
    if (e < E0) { src = ei[e]; dst = ei[E0 + e]; }
    else        { src = dst = e - E0; }
    int pos = row_off[dst] + atomicAdd(&cursor[dst], 1);
    csr_src[pos] = src;
}

// ---------------- fused fp32 -> bf16 weight conversion (4 segments) ----------------
__global__ __launch_bounds__(256) void cvt_bf16_fused_k(
    const float* __restrict__ p0, short* __restrict__ q0, int n0,
    const float* __restrict__ p1, short* __restrict__ q1, int n1,
    const float* __restrict__ p2, short* __restrict__ q2, int n2,
    const float* __restrict__ p3, short* __restrict__ q3, int n3) {
    int i = blockIdx.x * 256 + threadIdx.x;
    const float* in; short* out; int idx;
    if (i < n0) { in = p0; out = q0; idx = i; }
    else if (i < n0 + n1) { in = p1; out = q1; idx = i - n0; }
    else if (i < n0 + n1 + n2) { in = p2; out = q2; idx = i - n0 - n1; }
    else if (i < n0 + n1 + n2 + n3) { in = p3; out = q3; idx = i - n0 - n1 - n2; }
    else return;
    float4 v = ((const float4*)in)[idx];
    short4 o;
    o.x = f2bf(v.x); o.y = f2bf(v.y); o.z = f2bf(v.z); o.w = f2bf(v.w);
    ((short4*)out)[idx] = o;
}

// ---------------- K-pad fp32 [rows,K] -> bf16 [rows,Kp] (zero tail), 3 segments ----
__global__ __launch_bounds__(256) void pad_bf16_k(
    const float* __restrict__ p0, short* __restrict__ q0, int r0,
    const float* __restrict__ p1, short* __restrict__ q1, int r1,
    const float* __restrict__ p2, short* __restrict__ q2, int r2,
    int K, int Kp) {
    int i = blockIdx.x * 256 + threadIdx.x;
    int rows = r0 + r1 + r2;
    int total = rows * Kp;
    if (i >= total) return;
    int row = i / Kp, col = i - row * Kp;
    const float* in; short* out; int r;
    if (row < r0) { in = p0; out = q0; r = row; }
    else if (row < r0 + r1) { in = p1; out = q1; r = row - r0; }
    else { in = p2; out = q2; r = row - r0 - r1; }
    out[(size_t)r * Kp + col] = (col < K) ? f2bf(in[(size_t)r * K + col]) : (short)0;
}

// ---------------- dual-output bf16 MFMA GEMM (round-2 config: BK=32, 16KB LDS) ----
// Fused alpha writes non-atomic per-64-col-chunk partials ps/pd[chunk][m];
// alpha_reduce_k folds them into asrc/adst.
__global__ __launch_bounds__(256) void gemm_bf16_dual(
    const short* __restrict__ A, const short* __restrict__ B,
    const float* __restrict__ b1, const float* __restrict__ b2,
    const float* __restrict__ a_s, const float* __restrict__ a_d,
    float* __restrict__ ps, float* __restrict__ pd,
    short* __restrict__ Cb, void* __restrict__ Cf, int lin_bf16,
    int M, int Nh, int Nf, int K, int H) {
    __shared__ short As[128 * 32];
    __shared__ short Bs[128 * 32];
    const int t = threadIdx.x;
    const int wave = t >> 6, lane = t & 63;
    const int m0 = blockIdx.y * 128, n0 = blockIdx.x * 128;
    const int wm = (wave >> 1) * 64, wn = (wave & 1) * 64;
    const int lane15 = lane & 15, quad = lane >> 4;

    const int lrow = lane >> 2;                        // row within 16-row wave region
    const int lk = ((lane & 3) ^ ((lrow >> 1) & 3)) * 8;  // swizzled global k chunk
    int arow0 = m0 + wave * 16 + lrow;
    int arow1 = arow0 + 64;
    if (arow0 > M - 1) arow0 = M - 1;
    if (arow1 > M - 1) arow1 = M - 1;
    const short* ag0 = A + (size_t)arow0 * K + lk;
    const short* ag1 = A + (size_t)arow1 * K + lk;
    const short* bg0 = B + (size_t)(n0 + wave * 16 + lrow) * K + lk;
    const short* bg1 = B + (size_t)(n0 + 64 + wave * 16 + lrow) * K + lk;
    short* al0 = &As[(wave * 16) * 32];
    short* al1 = &As[(64 + wave * 16) * 32];
    short* bl0 = &Bs[(wave * 16) * 32];
    short* bl1 = &Bs[(64 + wave * 16) * 32];

    const int rql = (quad ^ ((lane15 >> 1) & 3)) * 8;  // swizzled read position

    f32x4 acc[4][4];
#pragma unroll
    for (int i = 0; i < 4; ++i)
#pragma unroll
        for (int j = 0; j < 4; ++j) acc[i][j] = (f32x4){0.f, 0.f, 0.f, 0.f};

    for (int k0 = 0; k0 < K; k0 += 32) {
        GLDS(ag0 + k0, al0);
        GLDS(ag1 + k0, al1);
        GLDS(bg0 + k0, bl0);
        GLDS(bg1 + k0, bl1);
        __syncthreads();
        bf16x8 af[4], bfr[4];
#pragma unroll
        for (int i = 0; i < 4; ++i)
            af[i] = *(const bf16x8*)&As[(wm + 16 * i + lane15) * 32 + rql];
#pragma unroll
        for (int j = 0; j < 4; ++j)
            bfr[j] = *(const bf16x8*)&Bs[(wn + 16 * j + lane15) * 32 + rql];
#pragma unroll
        for (int i = 0; i < 4; ++i)
#pragma unroll
            for (int j = 0; j < 4; ++j)
                acc[i][j] = __builtin_amdgcn_mfma_f32_16x16x32_bf16(
                    af[i], bfr[j], acc[i][j], 0, 0, 0);
        __syncthreads();
    }

    if (n0 >= Nh) {
        // linear-skip part: bias folded in; fp32 (layer 3 -> out) or bf16 (1-2)
#pragma unroll
        for (int j = 0; j < 4; ++j) {
            int nc = n0 - Nh + wn + 16 * j + lane15;
            float bias = b1[nc] + b2[nc];
#pragma unroll
            for (int i = 0; i < 4; ++i) {
                int mb = m0 + wm + 16 * i + quad * 4;
#pragma unroll
                for (int r = 0; r < 4; ++r) {
                    int m = mb + r;
                    if (m < M) {
                        float v = acc[i][j][r] + bias;
                        if (lin_bf16) ((short*)Cf)[(size_t)m * Nf + nc] = f2bf(v);
                        else          ((float*)Cf)[(size_t)m * Nf + nc] = v;
                    }
                }
            }
        }
    } else {
        // h part: store bf16 h + fused alpha chunk-partials (non-atomic).
        const int chunk = (n0 + wn) >> 6;
        const int head = chunk >> 2;               // DC=256 -> 4 chunks/head
        const int cb = (n0 + wn) & 255;
        float asv[4], adv[4];
#pragma unroll
        for (int j = 0; j < 4; ++j) {
            asv[j] = a_s[head * DC + cb + 16 * j + lane15];
            adv[j] = a_d[head * DC + cb + 16 * j + lane15];
        }
#pragma unroll
        for (int j = 0; j < 4; ++j) {
            int n = n0 + wn + 16 * j + lane15;
#pragma unroll
            for (int i = 0; i < 4; ++i) {
                int mb = m0 + wm + 16 * i + quad * 4;
#pragma unroll
                for (int r = 0; r < 4; ++r) {
                    int m = mb + r;
                    if (m < M) Cb[(size_t)m * Nh + n] = f2bf(acc[i][j][r]);
                }
            }
        }
        float* psc = ps + (size_t)chunk * M;
        float* pdc = pd + (size_t)chunk * M;
#pragma unroll
        for (int i = 0; i < 4; ++i) {
#pragma unroll
            for (int r = 0; r < 4; ++r) {
                float s = acc[i][0][r] * asv[0] + acc[i][1][r] * asv[1] +
                          acc[i][2][r] * asv[2] + acc[i][3][r] * asv[3];
                float d = acc[i][0][r] * adv[0] + acc[i][1][r] * adv[1] +
                          acc[i][2][r] * adv[2] + acc[i][3][r] * adv[3];
#pragma unroll
                for (int off = 8; off > 0; off >>= 1) {   // reduce 16 lanes (same quad)
                    s += __shfl_xor(s, off);
                    d += __shfl_xor(d, off);
                }
                int m = m0 + wm + 16 * i + quad * 4 + r;
                if (lane15 == 0 && m < M) { psc[m] = s; pdc[m] = d; }
            }
        }
    }
}

// ---------------- fold per-chunk alpha partials -> asrc/adst [M,H] ----------------
__global__ __launch_bounds__(256) void alpha_reduce_k(
    const float* __restrict__ ps, const float* __restrict__ pd,
    float* __restrict__ asrc, float* __restrict__ adst, int M, int H) {
    int m = blockIdx.x * 256 + threadIdx.x;
    int h = blockIdx.y;
    if (m >= M) return;
    float s = 0.f, d = 0.f;
#pragma unroll
    for (int c = 0; c < 4; ++c) {                  // 4 chunks per 256-wide head
        s += ps[(size_t)(h * 4 + c) * M + m];
        d += pd[(size_t)(h * 4 + c) * M + m];
    }
    asrc[m * H + h] = s;
    adst[m * H + h] = d;
}

// ---------------- GAT aggregation (round-2 structure + head-major XCD locality) ----
// One wave per (node, head), in-wave softmax, deg<=64 register fast path.
// Wave->work mapping is HEAD-MAJOR (wid = h*N + n) with the m204 bijective
// XCD-chunk block swizzle: each XCD processes a contiguous head-major range,
// so its hbuf gathers touch only one head's 512B slices (~5.1 MB hot set ~ L2).
// Requires gridDim.x % 8 == 0 (N*H/4 = 10000, exact).
__global__ __launch_bounds__(256) void gat_agg(
    const short* __restrict__ hbuf, const short* __restrict__ lin,
    const float* __restrict__ asrc, const float* __restrict__ adst_a,
    const int* __restrict__ row_off, const int* __restrict__ csr_src,
    short* __restrict__ outx, int N, int H) {
    const int NB = gridDim.x;
    const int b = blockIdx.x;
    const int q = NB >> 3;                       // NB % 8 == 0 by construction
    const int cb = (b & 7) * q + (b >> 3);       // bijective XCD-chunked block id
    int wid = cb * 4 + (int)(threadIdx.x >> 6);  // head-major work id
    int lane = threadIdx.x & 63;
    if (wid >= N * H) return;
    int hh = wid / N;                            // head (contiguous per XCD chunk)
    int n = wid - hh * N;
    int aidx = n * H + hh;
    int beg = row_off[n], end = row_off[n + 1];
    int deg = end - beg;
    float ad = adst_a[aidx];

    size_t cbase = (size_t)n * H * DC + hh * DC + lane * 4;
    const short4 lv = *(const short4*)(lin + cbase);
    float4 acc = make_float4(bf2f(lv.x), bf2f(lv.y), bf2f(lv.z), bf2f(lv.w));

    if (deg <= 64) {
        int s = 0; float e = -1e38f;
        if (lane < deg) {
            s = csr_src[beg + lane];
            e = lrelu02(asrc[s * H + hh] + ad);
        }
        float m = e;
#pragma unroll
        for (int off = 32; off > 0; off >>= 1) m = fmaxf(m, __shfl_xor(m, off));
        float p = (lane < deg) ? __expf(e - m) : 0.f;
        float dsum = p;
#pragma unroll
        for (int off = 32; off > 0; off >>= 1) dsum += __shfl_xor(dsum, off);
        float coef = p / (dsum + 1e-16f);

        const size_t hoff = (size_t)hh * DC + lane * 4;
        int i = 0;
        for (; i + 8 <= deg; i += 8) {
            short4 v[8]; float wv[8];
#pragma unroll
            for (int u = 0; u < 8; ++u) {
                int su = __shfl(s, i + u);
                v[u] = *(const short4*)(hbuf + (size_t)su * (H * DC) + hoff);
                wv[u] = __shfl(coef, i + u);
            }
#pragma unroll
            for (int u = 0; u < 8; ++u) {
                acc.x += wv[u] * bf2f(v[u].x);
                acc.y += wv[u] * bf2f(v[u].y);
                acc.z += wv[u] * bf2f(v[u].z);
                acc.w += wv[u] * bf2f(v[u].w);
            }
        }
        for (; i < deg; ++i) {
            float wv = __shfl(coef, i);
            int si = __shfl(s, i);
            const short4 hv = *(const short4*)(hbuf + (size_t)si * (H * DC) + hoff);
            acc.x += wv * bf2f(hv.x); acc.y += wv * bf2f(hv.y);
            acc.z += wv * bf2f(hv.z); acc.w += wv * bf2f(hv.w);
        }
    } else {
        float m = -1e38f;
        for (int i = beg + lane; i < end; i += 64) {
            int s = csr_src[i];
            m = fmaxf(m, lrelu02(asrc[s * H + hh] + ad));
        }
#pragma unroll
        for (int off = 32; off > 0; off >>= 1) m = fmaxf(m, __shfl_xor(m, off));
        float dsum = 0.f;
        for (int i = beg + lane; i < end; i += 64) {
            int s = csr_src[i];
            dsum += __expf(lrelu02(asrc[s * H + hh] + ad) - m);
        }
#pragma unroll
        for (int off = 32; off > 0; off >>= 1) dsum += __shfl_xor(dsum, off);
        float inv = 1.f / (dsum + 1e-16f);
        for (int i = beg; i < end; ++i) {
            int s = csr_src[i];
            float wv = __expf(lrelu02(asrc[s * H + hh] + ad) - m) * inv;
            const short4 hv = *(const short4*)(hbuf + ((size_t)s * H + hh) * DC + lane * 4);
            acc.x += wv * bf2f(hv.x); acc.y += wv * bf2f(hv.y);
            acc.z += wv * bf2f(hv.z); acc.w += wv * bf2f(hv.w);
        }
    }
    // ELU + bf16
    acc.x = acc.x > 0.f ? acc.x : __expf(acc.x) - 1.f;
    acc.y = acc.y > 0.f ? acc.y : __expf(acc.y) - 1.f;
    acc.z = acc.z > 0.f ? acc.z : __expf(acc.z) - 1.f;
    acc.w = acc.w > 0.f ? acc.w : __expf(acc.w) - 1.f;
    short4 o;
    o.x = f2bf(acc.x); o.y = f2bf(acc.y); o.z = f2bf(acc.z); o.w = f2bf(acc.w);
    *(short4*)(outx + cbase) = o;
}

// ---------------- Layer-3 aggregation: one block (6 waves) per node ---------------
__global__ __launch_bounds__(384) void gat_agg_mean(
    const short* __restrict__ hbuf, const float* __restrict__ asrc,
    const float* __restrict__ adst_a, const int* __restrict__ row_off,
    const int* __restrict__ csr_src, float* __restrict__ out, int N) {
    const int H = 6;
    __shared__ float red[6][DC];
    int n = blockIdx.x;
    int wave = threadIdx.x >> 6, lane = threadIdx.x & 63;
    int hh = wave;
    int beg = row_off[n], end = row_off[n + 1];
    int deg = end - beg;
    const float invH = 1.f / 6.f;
    float ad = adst_a[n * H + hh];

    float4 acc = make_float4(0.f, 0.f, 0.f, 0.f);
    const size_t hoff = (size_t)hh * DC + lane * 4;

    if (deg <= 64) {
        int s = 0; float e = -1e38f;
        if (lane < deg) {
            s = csr_src[beg + lane];
            e = lrelu02(asrc[s * H + hh] + ad);
        }
        float m = e;
#pragma unroll
        for (int off = 32; off > 0; off >>= 1) m = fmaxf(m, __shfl_xor(m, off));
        float p = (lane < deg) ? __expf(e - m) : 0.f;
        float dsum = p;
#pragma unroll
        for (int off = 32; off > 0; off >>= 1) dsum += __shfl_xor(dsum, off);
        float coef = p * invH / (dsum + 1e-16f);

        int i = 0;
        for (; i + 8 <= deg; i += 8) {
            short4 v[8]; float wv[8];
#pragma unroll
            for (int u = 0; u < 8; ++u) {
                int su = __shfl(s, i + u);
                v[u] = *(const short4*)(hbuf + (size_t)su * (H * DC) + hoff);
                wv[u] = __shfl(coef, i + u);
            }
#pragma unroll
            for (int u = 0; u < 8; ++u) {
                acc.x += wv[u] * bf2f(v[u].x);
                acc.y += wv[u] * bf2f(v[u].y);
                acc.z += wv[u] * bf2f(v[u].z);
                acc.w += wv[u] * bf2f(v[u].w);
            }
        }
        for (; i < deg; ++i) {
            float wv = __shfl(coef, i);
            int si = __shfl(s, i);
            const short4 hv = *(const short4*)(hbuf + (size_t)si * (H * DC) + hoff);
            acc.x += wv * bf2f(hv.x); acc.y += wv * bf2f(hv.y);
            acc.z += wv * bf2f(hv.z); acc.w += wv * bf2f(hv.w);
        }
    } else {
        float m = -1e38f;
        for (int i = beg + lane; i < end; i += 64) {
            int s = csr_src[i];
            m = fmaxf(m, lrelu02(asrc[s * H + hh] + ad));
        }
#pragma unroll
        for (int off = 32; off > 0; off >>= 1) m = fmaxf(m, __shfl_xor(m, off));
        float dsum = 0.f;
        for (int i = beg + lane; i < end; i += 64) {
            int s = csr_src[i];
            dsum += __expf(lrelu02(asrc[s * H + hh] + ad) - m);
        }
#pragma unroll
        for (int off = 32; off > 0; off >>= 1) dsum += __shfl_xor(dsum, off);
        float inv = invH / (dsum + 1e-16f);
        for (int i = beg; i < end; ++i) {
            int s = csr_src[i];
            float wv = __expf(lrelu02(asrc[s * H + hh] + ad) - m) * inv;
            const short4 hv = *(const short4*)(hbuf + (size_t)s * (H * DC) + hoff);
            acc.x += wv * bf2f(hv.x); acc.y += wv * bf2f(hv.y);
            acc.z += wv * bf2f(hv.z); acc.w += wv * bf2f(hv.w);
        }
    }
    *(float4*)&red[wave][lane * 4] = acc;
    __syncthreads();
    if (wave == 0) {
        float* op = out + (size_t)n * DC + lane * 4;
        float4 o = *(float4*)op;   // lin3 + b3 + lb3 preloaded by GEMM
#pragma unroll
        for (int j = 0; j < 6; ++j) {
            float4 r = *(float4*)&red[j][lane * 4];
            o.x += r.x; o.y += r.y; o.z += r.z; o.w += r.w;
        }
        *(float4*)op = o;
    }
}

// ---------------- launch ----------------
extern "C" void kernel_launch(void* const* d_in, const int* in_sizes, int n_in,
                              void* d_out, int out_size, void* d_ws, size_t ws_size,
                              hipStream_t stream) {
    const float* x   = (const float*)d_in[0];
    const int*   ei  = (const int*)d_in[1];
    const float* W1  = (const float*)d_in[2];
    const float* a1s = (const float*)d_in[3];
    const float* a1d = (const float*)d_in[4];
    const float* b1  = (const float*)d_in[5];
    const float* lw1 = (const float*)d_in[6];
    const float* lb1 = (const float*)d_in[7];
    const float* W2  = (const float*)d_in[8];
    const float* a2s = (const float*)d_in[9];
    const float* a2d = (const float*)d_in[10];
    const float* b2  = (const float*)d_in[11];
    const float* lb2_w = (const float*)d_in[12];
    const float* lb2 = (const float*)d_in[13];
    const float* W3  = (const float*)d_in[14];
    const float* a3s = (const float*)d_in[15];
    const float* a3d = (const float*)d_in[16];
    const float* b3  = (const float*)d_in[17];
    const float* lw3 = (const float*)d_in[18];
    const float* lb3 = (const float*)d_in[19];
    const float* lw2 = lb2_w;
    float* out = (float*)d_out;

    const int N = NN, E0 = EE0, E = EE0 + NN;

    unsigned char* w = (unsigned char*)d_ws;
    size_t off = 0;
    auto alloc = [&](size_t bytes) {
        void* p = w + off;
        off += (bytes + 255) & ~(size_t)255;
        return p;
    };
    short* hbuf   = (short*)alloc((size_t)N * 1536 * 2);  // h bf16 (max: layer 3)
    short* buf    = (short*)alloc((size_t)N * 1024 * 2);  // lin1/lin2 skip, bf16
    short* xb     = (short*)alloc((size_t)N * 1024 * 2);  // x1 bf16, then x2 bf16
    short* xpad   = (short*)alloc((size_t)N * 32 * 2);    // x zero-padded K=32 bf16
    short* W1p    = (short*)alloc((size_t)1024 * 32 * 2);       // + lw1p right after
    short* lw1p   = (short*)alloc((size_t)1024 * 32 * 2);
    short* W2b    = (short*)alloc((size_t)1024 * 1024 * 2);     // + lw2b right after
    short* lw2b   = (short*)alloc((size_t)1024 * 1024 * 2);
    short* W3b    = (short*)alloc((size_t)1536 * 1024 * 2);     // + lw3b right after
    short* lw3b   = (short*)alloc((size_t)256 * 1024 * 2);
    float* psrc   = (float*)alloc((size_t)24 * N * 4);   // alpha chunk-partials (src)
    float* pdst   = (float*)alloc((size_t)24 * N * 4);   // alpha chunk-partials (dst)
    float* asrc   = (float*)alloc((size_t)N * 6 * 4);
    float* adst   = (float*)alloc((size_t)N * 6 * 4);
    int* row_off  = (int*)alloc((size_t)(N + 1) * 4);
    int* counts2  = (int*)alloc((size_t)2 * N * 4);  // counts | cursor
    int* counts   = counts2;
    int* cursor   = counts2 + N;
    int* csr_src  = (int*)alloc((size_t)E * 4);
    (void)ws_size; (void)n_in; (void)in_sizes; (void)out_size;

    // ---- CSR build ----
    hipMemsetAsync(counts2, 0, (size_t)2 * N * 4, stream);
    count_edges_k<<<ceildiv(E, 256), 256, 0, stream>>>(ei, counts, E0, N);
    scan_k<<<1, 1024, 0, stream>>>(counts, row_off, N);
    scatter_k<<<ceildiv(E, 256), 256, 0, stream>>>(ei, row_off, cursor, csr_src, E0, N);

    // ---- weight bf16 conversion (fused) + K-pad for layer 1 ----
    {
        int q0 = 1024 * 1024 / 4, q1 = 1024 * 1024 / 4, q2 = 1536 * 1024 / 4,
            q3 = 256 * 1024 / 4;
        cvt_bf16_fused_k<<<ceildiv(q0 + q1 + q2 + q3, 256), 256, 0, stream>>>(
            W2, W2b, q0, lw2, lw2b, q1, W3, W3b, q2, lw3, lw3b, q3);
        int rows = N + 1024 + 1024;
        pad_bf16_k<<<ceildiv(rows * 32, 256), 256, 0, stream>>>(
            x, xpad, N, W1, W1p, 1024, lw1, lw1p, 1024, NF, 32);
    }

    // ---- Layer 1 (H=4, K=14 padded to 32): h->hbuf bf16, lin->buf bf16 ----
    gemm_bf16_dual<<<dim3(16, ceildiv(N, 128)), 256, 0, stream>>>(
        xpad, W1p, b1, lb1, a1s, a1d, psrc, pdst, hbuf, (void*)buf, 1,
        N, 1024, 1024, 32, 4);
    alpha_reduce_k<<<dim3(ceildiv(N, 256), 4), 256, 0, stream>>>(
        psrc, pdst, asrc, adst, N, 4);
    gat_agg<<<N * 4 / 4, 256, 0, stream>>>(hbuf, buf, asrc, adst, row_off,
                                           csr_src, xb, N, 4);

    // ---- Layer 2 (H=4, K=1024) ----
    gemm_bf16_dual<<<dim3(16, ceildiv(N, 128)), 256, 0, stream>>>(
        xb, W2b, b2, lb2, a2s, a2d, psrc, pdst, hbuf, (void*)buf, 1,
        N, 1024, 1024, 1024, 4);
    alpha_reduce_k<<<dim3(ceildiv(N, 256), 4), 256, 0, stream>>>(
        psrc, pdst, asrc, adst, N, 4);
    gat_agg<<<N * 4 / 4, 256, 0, stream>>>(hbuf, buf, asrc, adst, row_off,
                                           csr_src, xb, N, 4);

    // ---- Layer 3 (H=6, K=1024, mean heads): h->hbuf, lin->out fp32 ----
    gemm_bf16_dual<<<dim3(14, ceildiv(N, 128)), 256, 0, stream>>>(
        xb, W3b, b3, lb3, a3s, a3d, psrc, pdst, hbuf, (void*)out, 0,
        N, 1536, 256, 1024, 6);
    alpha_reduce_k<<<dim3(ceildiv(N, 256), 6), 256, 0, stream>>>(
        psrc, pdst, asrc, adst, N, 6);
    gat_agg_mean<<<N, 384, 0, stream>>>(hbuf, asrc, adst, row_off, csr_src, out, N);
}

// Round 6
// 425.373 us; speedup vs baseline: 1.2338x; 1.0402x over previous
//
#include <hip/hip_runtime.h>
#include <hip/hip_bf16.h>
#include <cstddef>

#define NN 10000      // nodes
#define EE0 160000    // raw edges (self-loops added on top)
#define NF 14
#define DC 256        // per-head channels

static inline int ceildiv(int a, int b) { return (a + b - 1) / b; }

__device__ __forceinline__ float lrelu02(float x) { return fmaxf(x, 0.2f * x); }

// round-to-nearest-even fp32 -> bf16 (as raw short)
__device__ __forceinline__ short f2bf(float f) {
    unsigned u = __float_as_uint(f);
    unsigned r = (u + 0x7FFFu + ((u >> 16) & 1u)) >> 16;
    return (short)r;
}
__device__ __forceinline__ float bf2f(short s) {
    return __uint_as_float(((unsigned)(unsigned short)s) << 16);
}

typedef __attribute__((ext_vector_type(8))) short bf16x8;
typedef __attribute__((ext_vector_type(4))) float f32x4;

#define GLDS(gaddr, laddr)                                                         \
    __builtin_amdgcn_global_load_lds(                                              \
        (__attribute__((address_space(1))) void*)(gaddr),                          \
        (__attribute__((address_space(3))) void*)(laddr), 16, 0, 0)

// ---------------- CSR build ----------------
__global__ void count_edges_k(const int* __restrict__ ei, int* __restrict__ counts,
                              int E0, int N) {
    int e = blockIdx.x * 256 + threadIdx.x;
    int E = E0 + N;
    if (e >= E) return;
    int dst = (e < E0) ? ei[E0 + e] : (e - E0);
    atomicAdd(&counts[dst], 1);
}

// 1024 threads; each scans a contiguous chunk; one 1024-wide LDS scan (10 steps).
__global__ __launch_bounds__(1024) void scan_k(const int* __restrict__ counts,
                                               int* __restrict__ row_off, int n) {
    __shared__ int sums[1024];
    int t = threadIdx.x;
    int chunk = (n + 1023) >> 10;
    int base = t * chunk;
    int lim = base + chunk; if (lim > n) lim = n;
    int s = 0;
    for (int i = base; i < lim; ++i) s += counts[i];
    sums[t] = s;
    __syncthreads();
    for (int off = 1; off < 1024; off <<= 1) {
        int v = (t >= off) ? sums[t - off] : 0;
        __syncthreads();
        sums[t] += v;
        __syncthreads();
    }
    int run = (t == 0) ? 0 : sums[t - 1];   // exclusive prefix of this chunk
    for (int i = base; i < lim; ++i) { run += counts[i]; row_off[i + 1] = run; }
    if (t == 0) row_off[0] = 0;
}

__global__ void scatter_k(const int* __restrict__ ei, const int* __restrict__ row_off,
                          int* __restrict__ cursor, int* __restrict__ csr_src,
                          int E0, int N) {
    int e = blockIdx.x * 256 + threadIdx.x;
    int E = E0 + N;
    if (e >= E) return;
    int src, dst;
    if (e < E0) { src = ei[e]; dst = ei[E0 + e]; }
    else        { src = dst = e - E0; }
    int pos = row_off[dst] + atomicAdd(&cursor[dst], 1);
    csr_src[pos] = src;
}

// ---------------- fused fp32 -> bf16 weight conversion (4 segments) ----------------
__global__ __launch_bounds__(256) void cvt_bf16_fused_k(
    const float* __restrict__ p0, short* __restrict__ q0, int n0,
    const float* __restrict__ p1, short* __restrict__ q1, int n1,
    const float* __restrict__ p2, short* __restrict__ q2, int n2,
    const float* __restrict__ p3, short* __restrict__ q3, int n3) {
    int i = blockIdx.x * 256 + threadIdx.x;
    const float* in; short* out; int idx;
    if (i < n0) { in = p0; out = q0; idx = i; }
    else if (i < n0 + n1) { in = p1; out = q1; idx = i - n0; }
    else if (i < n0 + n1 + n2) { in = p2; out = q2; idx = i - n0 - n1; }
    else if (i < n0 + n1 + n2 + n3) { in = p3; out = q3; idx = i - n0 - n1 - n2; }
    else return;
    float4 v = ((const float4*)in)[idx];
    short4 o;
    o.x = f2bf(v.x); o.y = f2bf(v.y); o.z = f2bf(v.z); o.w = f2bf(v.w);
    ((short4*)out)[idx] = o;
}

// ---------------- K-pad fp32 [rows,K] -> bf16 [rows,Kp] (zero tail), 3 segments ----
__global__ __launch_bounds__(256) void pad_bf16_k(
    const float* __restrict__ p0, short* __restrict__ q0, int r0,
    const float* __restrict__ p1, short* __restrict__ q1, int r1,
    const float* __restrict__ p2, short* __restrict__ q2, int r2,
    int K, int Kp) {
    int i = blockIdx.x * 256 + threadIdx.x;
    int rows = r0 + r1 + r2;
    int total = rows * Kp;
    if (i >= total) return;
    int row = i / Kp, col = i - row * Kp;
    const float* in; short* out; int r;
    if (row < r0) { in = p0; out = q0; r = row; }
    else if (row < r0 + r1) { in = p1; out = q1; r = row - r0; }
    else { in = p2; out = q2; r = row - r0 - r1; }
    out[(size_t)r * Kp + col] = (col < K) ? f2bf(in[(size_t)r * K + col]) : (short)0;
}

// ---------------- dual-output bf16 MFMA GEMM (round-2 config: BK=32, 16KB LDS) ----
// Fused alpha writes non-atomic per-64-col-chunk partials ps/pd[chunk][m];
// alpha_reduce_k folds them into asrc/adst.
__global__ __launch_bounds__(256) void gemm_bf16_dual(
    const short* __restrict__ A, const short* __restrict__ B,
    const float* __restrict__ b1, const float* __restrict__ b2,
    const float* __restrict__ a_s, const float* __restrict__ a_d,
    float* __restrict__ ps, float* __restrict__ pd,
    short* __restrict__ Cb, void* __restrict__ Cf, int lin_bf16,
    int M, int Nh, int Nf, int K, int H) {
    __shared__ short As[128 * 32];
    __shared__ short Bs[128 * 32];
    const int t = threadIdx.x;
    const int wave = t >> 6, lane = t & 63;
    const int m0 = blockIdx.y * 128, n0 = blockIdx.x * 128;
    const int wm = (wave >> 1) * 64, wn = (wave & 1) * 64;
    const int lane15 = lane & 15, quad = lane >> 4;

    const int lrow = lane >> 2;                        // row within 16-row wave region
    const int lk = ((lane & 3) ^ ((lrow >> 1) & 3)) * 8;  // swizzled global k chunk
    int arow0 = m0 + wave * 16 + lrow;
    int arow1 = arow0 + 64;
    if (arow0 > M - 1) arow0 = M - 1;
    if (arow1 > M - 1) arow1 = M - 1;
    const short* ag0 = A + (size_t)arow0 * K + lk;
    const short* ag1 = A + (size_t)arow1 * K + lk;
    const short* bg0 = B + (size_t)(n0 + wave * 16 + lrow) * K + lk;
    const short* bg1 = B + (size_t)(n0 + 64 + wave * 16 + lrow) * K + lk;
    short* al0 = &As[(wave * 16) * 32];
    short* al1 = &As[(64 + wave * 16) * 32];
    short* bl0 = &Bs[(wave * 16) * 32];
    short* bl1 = &Bs[(64 + wave * 16) * 32];

    const int rql = (quad ^ ((lane15 >> 1) & 3)) * 8;  // swizzled read position

    f32x4 acc[4][4];
#pragma unroll
    for (int i = 0; i < 4; ++i)
#pragma unroll
        for (int j = 0; j < 4; ++j) acc[i][j] = (f32x4){0.f, 0.f, 0.f, 0.f};

    for (int k0 = 0; k0 < K; k0 += 32) {
        GLDS(ag0 + k0, al0);
        GLDS(ag1 + k0, al1);
        GLDS(bg0 + k0, bl0);
        GLDS(bg1 + k0, bl1);
        __syncthreads();
        bf16x8 af[4], bfr[4];
#pragma unroll
        for (int i = 0; i < 4; ++i)
            af[i] = *(const bf16x8*)&As[(wm + 16 * i + lane15) * 32 + rql];
#pragma unroll
        for (int j = 0; j < 4; ++j)
            bfr[j] = *(const bf16x8*)&Bs[(wn + 16 * j + lane15) * 32 + rql];
#pragma unroll
        for (int i = 0; i < 4; ++i)
#pragma unroll
            for (int j = 0; j < 4; ++j)
                acc[i][j] = __builtin_amdgcn_mfma_f32_16x16x32_bf16(
                    af[i], bfr[j], acc[i][j], 0, 0, 0);
        __syncthreads();
    }

    if (n0 >= Nh) {
        // linear-skip part: bias folded in; fp32 (layer 3 -> out) or bf16 (1-2)
#pragma unroll
        for (int j = 0; j < 4; ++j) {
            int nc = n0 - Nh + wn + 16 * j + lane15;
            float bias = b1[nc] + b2[nc];
#pragma unroll
            for (int i = 0; i < 4; ++i) {
                int mb = m0 + wm + 16 * i + quad * 4;
#pragma unroll
                for (int r = 0; r < 4; ++r) {
                    int m = mb + r;
                    if (m < M) {
                        float v = acc[i][j][r] + bias;
                        if (lin_bf16) ((short*)Cf)[(size_t)m * Nf + nc] = f2bf(v);
                        else          ((float*)Cf)[(size_t)m * Nf + nc] = v;
                    }
                }
            }
        }
    } else {
        // h part: store bf16 h + fused alpha chunk-partials (non-atomic).
        const int chunk = (n0 + wn) >> 6;
        const int head = chunk >> 2;               // DC=256 -> 4 chunks/head
        const int cb = (n0 + wn) & 255;
        float asv[4], adv[4];
#pragma unroll
        for (int j = 0; j < 4; ++j) {
            asv[j] = a_s[head * DC + cb + 16 * j + lane15];
            adv[j] = a_d[head * DC + cb + 16 * j + lane15];
        }
#pragma unroll
        for (int j = 0; j < 4; ++j) {
            int n = n0 + wn + 16 * j + lane15;
#pragma unroll
            for (int i = 0; i < 4; ++i) {
                int mb = m0 + wm + 16 * i + quad * 4;
#pragma unroll
                for (int r = 0; r < 4; ++r) {
                    int m = mb + r;
                    if (m < M) Cb[(size_t)m * Nh + n] = f2bf(acc[i][j][r]);
                }
            }
        }
        float* psc = ps + (size_t)chunk * M;
        float* pdc = pd + (size_t)chunk * M;
#pragma unroll
        for (int i = 0; i < 4; ++i) {
#pragma unroll
            for (int r = 0; r < 4; ++r) {
                float s = acc[i][0][r] * asv[0] + acc[i][1][r] * asv[1] +
                          acc[i][2][r] * asv[2] + acc[i][3][r] * asv[3];
                float d = acc[i][0][r] * adv[0] + acc[i][1][r] * adv[1] +
                          acc[i][2][r] * adv[2] + acc[i][3][r] * adv[3];
#pragma unroll
                for (int off = 8; off > 0; off >>= 1) {   // reduce 16 lanes (same quad)
                    s += __shfl_xor(s, off);
                    d += __shfl_xor(d, off);
                }
                int m = m0 + wm + 16 * i + quad * 4 + r;
                if (lane15 == 0 && m < M) { psc[m] = s; pdc[m] = d; }
            }
        }
    }
}

// ---------------- fold per-chunk alpha partials -> asrc/adst [M,H] ----------------
__global__ __launch_bounds__(256) void alpha_reduce_k(
    const float* __restrict__ ps, const float* __restrict__ pd,
    float* __restrict__ asrc, float* __restrict__ adst, int M, int H) {
    int m = blockIdx.x * 256 + threadIdx.x;
    int h = blockIdx.y;
    if (m >= M) return;
    float s = 0.f, d = 0.f;
#pragma unroll
    for (int c = 0; c < 4; ++c) {                  // 4 chunks per 256-wide head
        s += ps[(size_t)(h * 4 + c) * M + m];
        d += pd[(size_t)(h * 4 + c) * M + m];
    }
    asrc[m * H + h] = s;
    adst[m * H + h] = d;
}

// ---------------- GAT aggregation (head-major XCD locality, layers 1-2) ----------
// One wave per (node, head), in-wave softmax, deg<=64 register fast path.
// HEAD-MAJOR wid (= h*N + n) + m204 bijective XCD-chunk block swizzle: each XCD
// gathers only ~one head slice (~5.1 MB hot set ~ L2). gridDim.x % 8 == 0.
__global__ __launch_bounds__(256) void gat_agg(
    const short* __restrict__ hbuf, const short* __restrict__ lin,
    const float* __restrict__ asrc, const float* __restrict__ adst_a,
    const int* __restrict__ row_off, const int* __restrict__ csr_src,
    short* __restrict__ outx, int N, int H) {
    const int NB = gridDim.x;
    const int b = blockIdx.x;
    const int q = NB >> 3;                       // NB % 8 == 0 by construction
    const int cb = (b & 7) * q + (b >> 3);       // bijective XCD-chunked block id
    int wid = cb * 4 + (int)(threadIdx.x >> 6);  // head-major work id
    int lane = threadIdx.x & 63;
    if (wid >= N * H) return;
    int hh = wid / N;                            // head (contiguous per XCD chunk)
    int n = wid - hh * N;
    int aidx = n * H + hh;
    int beg = row_off[n], end = row_off[n + 1];
    int deg = end - beg;
    float ad = adst_a[aidx];

    size_t cbase = (size_t)n * H * DC + hh * DC + lane * 4;
    const short4 lv = *(const short4*)(lin + cbase);
    float4 acc = make_float4(bf2f(lv.x), bf2f(lv.y), bf2f(lv.z), bf2f(lv.w));

    if (deg <= 64) {
        int s = 0; float e = -1e38f;
        if (lane < deg) {
            s = csr_src[beg + lane];
            e = lrelu02(asrc[s * H + hh] + ad);
        }
        float m = e;
#pragma unroll
        for (int off = 32; off > 0; off >>= 1) m = fmaxf(m, __shfl_xor(m, off));
        float p = (lane < deg) ? __expf(e - m) : 0.f;
        float dsum = p;
#pragma unroll
        for (int off = 32; off > 0; off >>= 1) dsum += __shfl_xor(dsum, off);
        float coef = p / (dsum + 1e-16f);

        const size_t hoff = (size_t)hh * DC + lane * 4;
        int i = 0;
        for (; i + 8 <= deg; i += 8) {
            short4 v[8]; float wv[8];
#pragma unroll
            for (int u = 0; u < 8; ++u) {
                int su = __shfl(s, i + u);
                v[u] = *(const short4*)(hbuf + (size_t)su * (H * DC) + hoff);
                wv[u] = __shfl(coef, i + u);
            }
#pragma unroll
            for (int u = 0; u < 8; ++u) {
                acc.x += wv[u] * bf2f(v[u].x);
                acc.y += wv[u] * bf2f(v[u].y);
                acc.z += wv[u] * bf2f(v[u].z);
                acc.w += wv[u] * bf2f(v[u].w);
            }
        }
        for (; i < deg; ++i) {
            float wv = __shfl(coef, i);
            int si = __shfl(s, i);
            const short4 hv = *(const short4*)(hbuf + (size_t)si * (H * DC) + hoff);
            acc.x += wv * bf2f(hv.x); acc.y += wv * bf2f(hv.y);
            acc.z += wv * bf2f(hv.z); acc.w += wv * bf2f(hv.w);
        }
    } else {
        float m = -1e38f;
        for (int i = beg + lane; i < end; i += 64) {
            int s = csr_src[i];
            m = fmaxf(m, lrelu02(asrc[s * H + hh] + ad));
        }
#pragma unroll
        for (int off = 32; off > 0; off >>= 1) m = fmaxf(m, __shfl_xor(m, off));
        float dsum = 0.f;
        for (int i = beg + lane; i < end; i += 64) {
            int s = csr_src[i];
            dsum += __expf(lrelu02(asrc[s * H + hh] + ad) - m);
        }
#pragma unroll
        for (int off = 32; off > 0; off >>= 1) dsum += __shfl_xor(dsum, off);
        float inv = 1.f / (dsum + 1e-16f);
        for (int i = beg; i < end; ++i) {
            int s = csr_src[i];
            float wv = __expf(lrelu02(asrc[s * H + hh] + ad) - m) * inv;
            const short4 hv = *(const short4*)(hbuf + ((size_t)s * H + hh) * DC + lane * 4);
            acc.x += wv * bf2f(hv.x); acc.y += wv * bf2f(hv.y);
            acc.z += wv * bf2f(hv.z); acc.w += wv * bf2f(hv.w);
        }
    }
    // ELU + bf16
    acc.x = acc.x > 0.f ? acc.x : __expf(acc.x) - 1.f;
    acc.y = acc.y > 0.f ? acc.y : __expf(acc.y) - 1.f;
    acc.z = acc.z > 0.f ? acc.z : __expf(acc.z) - 1.f;
    acc.w = acc.w > 0.f ? acc.w : __expf(acc.w) - 1.f;
    short4 o;
    o.x = f2bf(acc.x); o.y = f2bf(acc.y); o.z = f2bf(acc.z); o.w = f2bf(acc.w);
    *(short4*)(outx + cbase) = o;
}

// ---------------- Layer-3 aggregation, head-major (same locality mechanism) -------
// One wave per (node, head), H=6, XCD-chunked head-major mapping; coef pre-scaled
// by 1/6; writes bf16 per-head partials red[h][n][256]. No lin/ELU here.
__global__ __launch_bounds__(256) void gat_agg6(
    const short* __restrict__ hbuf, const float* __restrict__ asrc,
    const float* __restrict__ adst_a, const int* __restrict__ row_off,
    const int* __restrict__ csr_src, short* __restrict__ red, int N) {
    const int H = 6;
    const int NB = gridDim.x;                    // N*6/4 = 15000, % 8 == 0
    const int b = blockIdx.x;
    const int q = NB >> 3;
    const int cb = (b & 7) * q + (b >> 3);
    int wid = cb * 4 + (int)(threadIdx.x >> 6);
    int lane = threadIdx.x & 63;
    if (wid >= N * H) return;
    int hh = wid / N;
    int n = wid - hh * N;
    int beg = row_off[n], end = row_off[n + 1];
    int deg = end - beg;
    const float invH = 1.f / 6.f;
    float ad = adst_a[n * H + hh];

    float4 acc = make_float4(0.f, 0.f, 0.f, 0.f);
    const size_t hoff = (size_t)hh * DC + lane * 4;

    if (deg <= 64) {
        int s = 0; float e = -1e38f;
        if (lane < deg) {
            s = csr_src[beg + lane];
            e = lrelu02(asrc[s * H + hh] + ad);
        }
        float m = e;
#pragma unroll
        for (int off = 32; off > 0; off >>= 1) m = fmaxf(m, __shfl_xor(m, off));
        float p = (lane < deg) ? __expf(e - m) : 0.f;
        float dsum = p;
#pragma unroll
        for (int off = 32; off > 0; off >>= 1) dsum += __shfl_xor(dsum, off);
        float coef = p * invH / (dsum + 1e-16f);

        int i = 0;
        for (; i + 8 <= deg; i += 8) {
            short4 v[8]; float wv[8];
#pragma unroll
            for (int u = 0; u < 8; ++u) {
                int su = __shfl(s, i + u);
                v[u] = *(const short4*)(hbuf + (size_t)su * (H * DC) + hoff);
                wv[u] = __shfl(coef, i + u);
            }
#pragma unroll
            for (int u = 0; u < 8; ++u) {
                acc.x += wv[u] * bf2f(v[u].x);
                acc.y += wv[u] * bf2f(v[u].y);
                acc.z += wv[u] * bf2f(v[u].z);
                acc.w += wv[u] * bf2f(v[u].w);
            }
        }
        for (; i < deg; ++i) {
            float wv = __shfl(coef, i);
            int si = __shfl(s, i);
            const short4 hv = *(const short4*)(hbuf + (size_t)si * (H * DC) + hoff);
            acc.x += wv * bf2f(hv.x); acc.y += wv * bf2f(hv.y);
            acc.z += wv * bf2f(hv.z); acc.w += wv * bf2f(hv.w);
        }
    } else {
        float m = -1e38f;
        for (int i = beg + lane; i < end; i += 64) {
            int s = csr_src[i];
            m = fmaxf(m, lrelu02(asrc[s * H + hh] + ad));
        }
#pragma unroll
        for (int off = 32; off > 0; off >>= 1) m = fmaxf(m, __shfl_xor(m, off));
        float dsum = 0.f;
        for (int i = beg + lane; i < end; i += 64) {
            int s = csr_src[i];
            dsum += __expf(lrelu02(asrc[s * H + hh] + ad) - m);
        }
#pragma unroll
        for (int off = 32; off > 0; off >>= 1) dsum += __shfl_xor(dsum, off);
        float inv = invH / (dsum + 1e-16f);
        for (int i = beg; i < end; ++i) {
            int s = csr_src[i];
            float wv = __expf(lrelu02(asrc[s * H + hh] + ad) - m) * inv;
            const short4 hv = *(const short4*)(hbuf + (size_t)s * (H * DC) + hoff);
            acc.x += wv * bf2f(hv.x); acc.y += wv * bf2f(hv.y);
            acc.z += wv * bf2f(hv.z); acc.w += wv * bf2f(hv.w);
        }
    }
    short4 o;
    o.x = f2bf(acc.x); o.y = f2bf(acc.y); o.z = f2bf(acc.z); o.w = f2bf(acc.w);
    *(short4*)(red + ((size_t)hh * N + n) * DC + lane * 4) = o;
}

// ---------------- sum 6 head partials into out (lin3+b3+lb3 preloaded) ------------
__global__ __launch_bounds__(256) void mean_reduce_k(
    const short* __restrict__ red, float* __restrict__ out, int N) {
    int i = blockIdx.x * 256 + threadIdx.x;      // 8 channels per thread
    int total = N * (DC / 8);
    if (i >= total) return;
    int n = i >> 5;                              // DC/8 = 32 slots per node
    int c8 = (i & 31) * 8;
    float* op = out + (size_t)n * DC + c8;
    float o[8];
    {
        float4 a = *(float4*)op;
        float4 b = *(float4*)(op + 4);
        o[0] = a.x; o[1] = a.y; o[2] = a.z; o[3] = a.w;
        o[4] = b.x; o[5] = b.y; o[6] = b.z; o[7] = b.w;
    }
#pragma unroll
    for (int h = 0; h < 6; ++h) {
        bf16x8 v = *(const bf16x8*)(red + ((size_t)h * N + n) * DC + c8);
#pragma unroll
        for (int j = 0; j < 8; ++j) o[j] += bf2f(v[j]);
    }
    *(float4*)op       = make_float4(o[0], o[1], o[2], o[3]);
    *(float4*)(op + 4) = make_float4(o[4], o[5], o[6], o[7]);
}

// ---------------- launch ----------------
extern "C" void kernel_launch(void* const* d_in, const int* in_sizes, int n_in,
                              void* d_out, int out_size, void* d_ws, size_t ws_size,
                              hipStream_t stream) {
    const float* x   = (const float*)d_in[0];
    const int*   ei  = (const int*)d_in[1];
    const float* W1  = (const float*)d_in[2];
    const float* a1s = (const float*)d_in[3];
    const float* a1d = (const float*)d_in[4];
    const float* b1  = (const float*)d_in[5];
    const float* lw1 = (const float*)d_in[6];
    const float* lb1 = (const float*)d_in[7];
    const float* W2  = (const float*)d_in[8];
    const float* a2s = (const float*)d_in[9];
    const float* a2d = (const float*)d_in[10];
    const float* b2  = (const float*)d_in[11];
    const float* lb2_w = (const float*)d_in[12];
    const float* lb2 = (const float*)d_in[13];
    const float* W3  = (const float*)d_in[14];
    const float* a3s = (const float*)d_in[15];
    const float* a3d = (const float*)d_in[16];
    const float* b3  = (const float*)d_in[17];
    const float* lw3 = (const float*)d_in[18];
    const float* lb3 = (const float*)d_in[19];
    const float* lw2 = lb2_w;
    float* out = (float*)d_out;

    const int N = NN, E0 = EE0, E = EE0 + NN;

    unsigned char* w = (unsigned char*)d_ws;
    size_t off = 0;
    auto alloc = [&](size_t bytes) {
        void* p = w + off;
        off += (bytes + 255) & ~(size_t)255;
        return p;
    };
    short* hbuf   = (short*)alloc((size_t)N * 1536 * 2);  // h bf16 (max: layer 3)
    short* buf    = (short*)alloc((size_t)N * 1024 * 2);  // lin1/lin2 skip, bf16
    short* xb     = (short*)alloc((size_t)N * 1024 * 2);  // x1 bf16, then x2 bf16
    short* xpad   = (short*)alloc((size_t)N * 32 * 2);    // x zero-padded K=32 bf16
    short* W1p    = (short*)alloc((size_t)1024 * 32 * 2);       // + lw1p right after
    short* lw1p   = (short*)alloc((size_t)1024 * 32 * 2);
    short* W2b    = (short*)alloc((size_t)1024 * 1024 * 2);     // + lw2b right after
    short* lw2b   = (short*)alloc((size_t)1024 * 1024 * 2);
    short* W3b    = (short*)alloc((size_t)1536 * 1024 * 2);     // + lw3b right after
    short* lw3b   = (short*)alloc((size_t)256 * 1024 * 2);
    float* psrc   = (float*)alloc((size_t)24 * N * 4);   // alpha chunk-partials (src)
    float* pdst   = (float*)alloc((size_t)24 * N * 4);   // alpha chunk-partials (dst)
    float* asrc   = (float*)alloc((size_t)N * 6 * 4);
    float* adst   = (float*)alloc((size_t)N * 6 * 4);
    int* row_off  = (int*)alloc((size_t)(N + 1) * 4);
    int* counts2  = (int*)alloc((size_t)2 * N * 4);  // counts | cursor
    int* counts   = counts2;
    int* cursor   = counts2 + N;
    int* csr_src  = (int*)alloc((size_t)E * 4);
    (void)ws_size; (void)n_in; (void)in_sizes; (void)out_size;

    // layer-3 per-head partials (bf16, [6][N][256] = 30.7 MB) ALIAS buf+xb
    // (contiguous 41 MB, both dead after the layer-3 GEMM completes).
    short* red = buf;

    // ---- CSR build ----
    hipMemsetAsync(counts2, 0, (size_t)2 * N * 4, stream);
    count_edges_k<<<ceildiv(E, 256), 256, 0, stream>>>(ei, counts, E0, N);
    scan_k<<<1, 1024, 0, stream>>>(counts, row_off, N);
    scatter_k<<<ceildiv(E, 256), 256, 0, stream>>>(ei, row_off, cursor, csr_src, E0, N);

    // ---- weight bf16 conversion (fused) + K-pad for layer 1 ----
    {
        int q0 = 1024 * 1024 / 4, q1 = 1024 * 1024 / 4, q2 = 1536 * 1024 / 4,
            q3 = 256 * 1024 / 4;
        cvt_bf16_fused_k<<<ceildiv(q0 + q1 + q2 + q3, 256), 256, 0, stream>>>(
            W2, W2b, q0, lw2, lw2b, q1, W3, W3b, q2, lw3, lw3b, q3);
        int rows = N + 1024 + 1024;
        pad_bf16_k<<<ceildiv(rows * 32, 256), 256, 0, stream>>>(
            x, xpad, N, W1, W1p, 1024, lw1, lw1p, 1024, NF, 32);
    }

    // ---- Layer 1 (H=4, K=14 padded to 32): h->hbuf bf16, lin->buf bf16 ----
    gemm_bf16_dual<<<dim3(16, ceildiv(N, 128)), 256, 0, stream>>>(
        xpad, W1p, b1, lb1, a1s, a1d, psrc, pdst, hbuf, (void*)buf, 1,
        N, 1024, 1024, 32, 4);
    alpha_reduce_k<<<dim3(ceildiv(N, 256), 4), 256, 0, stream>>>(
        psrc, pdst, asrc, adst, N, 4);
    gat_agg<<<N * 4 / 4, 256, 0, stream>>>(hbuf, buf, asrc, adst, row_off,
                                           csr_src, xb, N, 4);

    // ---- Layer 2 (H=4, K=1024) ----
    gemm_bf16_dual<<<dim3(16, ceildiv(N, 128)), 256, 0, stream>>>(
        xb, W2b, b2, lb2, a2s, a2d, psrc, pdst, hbuf, (void*)buf, 1,
        N, 1024, 1024, 1024, 4);
    alpha_reduce_k<<<dim3(ceildiv(N, 256), 4), 256, 0, stream>>>(
        psrc, pdst, asrc, adst, N, 4);
    gat_agg<<<N * 4 / 4, 256, 0, stream>>>(hbuf, buf, asrc, adst, row_off,
                                           csr_src, xb, N, 4);

    // ---- Layer 3 (H=6, K=1024, mean heads): h->hbuf, lin->out fp32 ----
    gemm_bf16_dual<<<dim3(14, ceildiv(N, 128)), 256, 0, stream>>>(
        xb, W3b, b3, lb3, a3s, a3d, psrc, pdst, hbuf, (void*)out, 0,
        N, 1536, 256, 1024, 6);
    alpha_reduce_k<<<dim3(ceildiv(N, 256), 6), 256, 0, stream>>>(
        psrc, pdst, asrc, adst, N, 6);
    gat_agg6<<<N * 6 / 4, 256, 0, stream>>>(hbuf, asrc, adst, row_off, csr_src,
                                            red, N);
    mean_reduce_k<<<ceildiv(N * 32, 256), 256, 0, stream>>>(red, out, N);
}